// Round 12
// baseline (251.232 us; speedup 1.0000x reference)
//
#include <hip/hip_runtime.h>
#include <hip/hip_bf16.h>

#define BB 64
#define NN 6272      // H*W*C = 196*32
#define OO 10
#define TPB 320      // 32 c x 10 o
#define EPSF 1e-9f
#define LOG2E 1.44269504f
#define HLOG2E 0.72134752f   // 0.5*log2(e)

#define EXP2F(x) __builtin_amdgcn_exp2f(x)   // v_exp_f32; __exp2f doesn't exist in HIP

// workspace offsets (floats)
#define ACC_PER_IT 21120            // B*O*33
#define OFF_ACC 0                   // 3 * 21120

// ---------------- iter-0 specialized pass (moments) ----------------
// grid 14x64 (vs R8's 7x64): 2x blocks, 14 hw rows each -> better overlap
// of the latency-bound transform loop.
__global__ __launch_bounds__(TPB, 3) void fc_pass0(
    const float* __restrict__ pose, const float* __restrict__ actv,
    const float* __restrict__ wgt, float* __restrict__ acc)
{
    __shared__ float smem0[5 * 2208];       // [wave][c][69] slices, 44160 B

    const int t = threadIdx.x;
    const int lane = t & 63;
    const int wv = t >> 6;                  // 0..4
    const int c = lane & 31;
    const int slot = t >> 5;                // 0..9
    const int chunk = blockIdx.x;           // 0..13 (14 hw rows each)
    const int b = blockIdx.y;

    float A1[16], M[40], Vw[4], Vh[4];
    float S0 = 0.f, Uw = 0.f, Uh = 0.f, sw2 = 0.f, sh2 = 0.f;
    #pragma unroll
    for (int k = 0; k < 16; k++) A1[k] = 0.f;
    #pragma unroll
    for (int k = 0; k < 40; k++) M[k] = 0.f;
    #pragma unroll
    for (int k = 0; k < 4; k++) { Vw[k] = 0.f; Vh[k] = 0.f; }

    for (int r = 0; r < 2; r++) {
        const int hl = slot + 10 * r;
        if (hl >= 14) break;                 // slots 4..9 do 1 row, 0..3 do 2
        const int hw = chunk * 14 + hl;
        const int hi = hw / 14;
        const int wi = hw - hi * 14;
        const float offw = (wi + 0.5f) * (1.0f / 14.0f);
        const float offh = (hi + 0.5f) * (1.0f / 14.0f);
        const size_t row = (size_t)b * NN + (hw << 5) + c;

        const float4* pp = (const float4*)(pose + row * 16);
        float4 q0 = pp[0], q1 = pp[1], q2 = pp[2], q3 = pp[3];
        const float a = actv[row];
        const float ra = 0.1f * a;
        const float raw = ra * offw, rah = ra * offh;
        S0 += ra; Uw += raw; Uh += rah;
        sw2 = fmaf(raw, offw, sw2); sh2 = fmaf(rah, offh, sh2);

        #define FOLD_I(qq, i)                                              \
        {                                                                  \
            const float x = qq.x, y = qq.y, z = qq.z, w = qq.w;            \
            const float t0 = ra * x, t1 = ra * y, t2 = ra * z, t3 = ra * w;\
            A1[i*4+0] += t0; A1[i*4+1] += t1;                              \
            A1[i*4+2] += t2; A1[i*4+3] += t3;                              \
            M[i*10+0] = fmaf(t0, x, M[i*10+0]);                            \
            M[i*10+1] = fmaf(t0, y, M[i*10+1]);                            \
            M[i*10+2] = fmaf(t0, z, M[i*10+2]);                            \
            M[i*10+3] = fmaf(t0, w, M[i*10+3]);                            \
            M[i*10+4] = fmaf(t1, y, M[i*10+4]);                            \
            M[i*10+5] = fmaf(t1, z, M[i*10+5]);                            \
            M[i*10+6] = fmaf(t1, w, M[i*10+6]);                            \
            M[i*10+7] = fmaf(t2, z, M[i*10+7]);                            \
            M[i*10+8] = fmaf(t2, w, M[i*10+8]);                            \
            M[i*10+9] = fmaf(t3, w, M[i*10+9]);                            \
        }
        FOLD_I(q0, 0) FOLD_I(q1, 1) FOLD_I(q2, 2) FOLD_I(q3, 3)
        #undef FOLD_I
        Vw[0] = fmaf(raw, q0.x, Vw[0]); Vw[1] = fmaf(raw, q0.y, Vw[1]);
        Vw[2] = fmaf(raw, q0.z, Vw[2]); Vw[3] = fmaf(raw, q0.w, Vw[3]);
        Vh[0] = fmaf(rah, q1.x, Vh[0]); Vh[1] = fmaf(rah, q1.y, Vh[1]);
        Vh[2] = fmaf(rah, q1.z, Vh[2]); Vh[3] = fmaf(rah, q1.w, Vh[3]);
    }

    float* myrow = &smem0[wv * 2208 + c * 69];
    #define FOLDW(arr, n, base)                                            \
    _Pragma("unroll")                                                      \
    for (int k2 = 0; k2 < n; k2++) {                                       \
        float x = arr[k2] + __shfl_xor(arr[k2], 32, 64);                   \
        if (lane < 32) myrow[base + k2] = x;                               \
    }
    FOLDW(A1, 16, 0) FOLDW(M, 40, 16) FOLDW(Vw, 4, 56) FOLDW(Vh, 4, 60)
    #undef FOLDW
    {
        float x0 = S0 + __shfl_xor(S0, 32, 64);
        float x1 = Uw + __shfl_xor(Uw, 32, 64);
        float x2 = Uh + __shfl_xor(Uh, 32, 64);
        float x3 = sw2 + __shfl_xor(sw2, 32, 64);
        float x4 = sh2 + __shfl_xor(sh2, 32, 64);
        if (lane < 32) {
            myrow[64] = x0; myrow[65] = x1; myrow[66] = x2;
            myrow[67] = x3; myrow[68] = x4;
        }
    }
    __syncthreads();
    for (int e = t; e < 2208; e += TPB) {
        smem0[e] = smem0[e] + smem0[2208 + e] + smem0[2*2208 + e]
                 + smem0[3*2208 + e] + smem0[4*2208 + e];
    }
    __syncthreads();

    const int oo = t >> 5, k = t & 31;
    float* ab = acc + ((size_t)b * OO + oo) * 33;
    if (k < 16) {
        const int i = k >> 2, kk = k & 3;
        float s = 0.f, s0acc = 0.f;
        #pragma unroll 4
        for (int cc = 0; cc < 32; cc++) {
            const float* mc = &smem0[cc * 69];
            const float* wc = wgt + cc * 160 + oo * 16 + kk;
            const float w0 = wc[0], w1 = wc[4], w2 = wc[8], w3 = wc[12];
            s += w0*mc[i*4+0] + w1*mc[i*4+1] + w2*mc[i*4+2] + w3*mc[i*4+3];
            if (k == 3) s += mc[65];
            if (k == 7) s += mc[66];
            if (k == 0) s0acc += mc[64];
        }
        atomicAdd(&ab[k], s);
        if (k == 0) atomicAdd(&ab[32], s0acc);
    } else {
        const int km = k - 16, i = km >> 2, kk = km & 3;
        float s = 0.f;
        #pragma unroll 4
        for (int cc = 0; cc < 32; cc++) {
            const float* mc = &smem0[cc * 69];
            const float* mi = mc + 16 + i * 10;
            const float* wc = wgt + cc * 160 + oo * 16 + kk;
            const float w0 = wc[0], w1 = wc[4], w2 = wc[8], w3 = wc[12];
            float q = w0*(w0*mi[0] + 2.f*(w1*mi[1] + w2*mi[2] + w3*mi[3]))
                    + w1*(w1*mi[4] + 2.f*(w2*mi[5] + w3*mi[6]))
                    + w2*(w2*mi[7] + 2.f*w3*mi[8])
                    + w3*(w3*mi[9]);
            s += q;
            if (km == 3) s += 2.f*(w0*mc[56]+w1*mc[57]+w2*mc[58]+w3*mc[59]) + mc[67];
            if (km == 7) s += 2.f*(w0*mc[60]+w1*mc[61]+w2*mc[62]+w3*mc[63]) + mc[68];
        }
        atomicAdd(&ab[k], s);
    }
}

// ---------------- iters 1-2: 14-step body, fused stats, log2-domain ----------------
// Logits in log2 domain: iv2 = 0.5*log2e*iv, sum(mu^2*iv2) folded into
// bias2 -> sq is 32 FMA vs 48; v_exp_f32 via __builtin_amdgcn_exp2f
// (kills the x*log2e mul inside __expf, 10/step); own = exp2(lg-mx)
// kills the 9-cndmask select chain. R10: pass is VALU-issue-bound ->
// 14-step blocks amortize prologue/epilogue best.
__global__ __launch_bounds__(TPB, 3) void fc_pass(
    const float* __restrict__ pose, const float* __restrict__ actv,
    const float* __restrict__ wgt,
    const float* __restrict__ accPrev,
    const float* __restrict__ beta_a, const float* __restrict__ beta_u,
    float* __restrict__ accOut, float inv_temp)
{
    __shared__ float smem[TPB * 17];   // logits: first 704 floats; epilogue table 5440

    const int t = threadIdx.x;
    const int c = t & 31;
    const int o = t >> 5;               // 0..9
    const int hi = blockIdx.x;          // 0..13
    const int b  = blockIdx.y;

    float wr[16];
    {
        const float4* wp = (const float4*)(wgt + ((c * OO + o) << 4));
        float4 a0 = wp[0], a1 = wp[1], a2 = wp[2], a3 = wp[3];
        wr[0]=a0.x; wr[1]=a0.y; wr[2]=a0.z; wr[3]=a0.w;
        wr[4]=a1.x; wr[5]=a1.y; wr[6]=a1.z; wr[7]=a1.w;
        wr[8]=a2.x; wr[9]=a2.y; wr[10]=a2.z; wr[11]=a2.w;
        wr[12]=a3.x; wr[13]=a3.y; wr[14]=a3.z; wr[15]=a3.w;
    }

    // fused stats from previous pass's acc, pre-transformed to log2 domain
    float iv2[16], m2iv[16], bias2;
    {
        const float* ab = accPrev + ((size_t)b * OO + o) * 33;
        const float S0p = ab[32];
        const float rs = S0p + EPSF;
        const float rsi = 1.f / rs;
        float sv = 0.f, csum = 0.f;
        #pragma unroll
        for (int d = 0; d < 16; d++) {
            const float s1 = ab[d], s2 = ab[16 + d];
            const float m = s1 * rsi;
            float vraw = fmaf(m * m, S0p, fmaf(-2.f * m, s1, s2));
            vraw = fmaxf(vraw, 0.f);
            const float var = fmaf(vraw, rsi, EPSF);
            sv += __logf(var);
            const float ivd = 1.f / var;
            const float i2 = ivd * HLOG2E;
            iv2[d] = i2;
            m2iv[d] = 2.f * m * i2;
            csum = fmaf(m * m, i2, csum);
        }
        const float cost = rs * fmaf(0.5f, sv, 16.f * beta_u[o]);
        const float act = 1.f / (1.f + __expf(-inv_temp * (beta_a[o] - cost)));
        const float biasN = __logf(act + EPSF) - 0.5f * sv;
        bias2 = fmaf(biasN, LOG2E, -csum);
    }

    float S1[16], S2[16], S0 = 0.f;
    #pragma unroll
    for (int d = 0; d < 16; d++) { S1[d] = 0.f; S2[d] = 0.f; }

    const size_t baseN = (size_t)b * NN + hi * 448;
    const float offh = (hi + 0.5f) * (1.0f / 14.0f);

    for (int s = 0; s < 14; s++) {
        const float offw = (s + 0.5f) * (1.0f / 14.0f);
        const int n = s * 32 + c;

        const float4* pp = (const float4*)(pose + (baseN + n) * 16);
        float4 q0 = pp[0], q1 = pp[1], q2 = pp[2], q3 = pp[3];
        const float a = actv[baseN + n];

        float p[16];
        p[0]=q0.x; p[1]=q0.y; p[2]=q0.z; p[3]=q0.w;
        p[4]=q1.x; p[5]=q1.y; p[6]=q1.z; p[7]=q1.w;
        p[8]=q2.x; p[9]=q2.y; p[10]=q2.z; p[11]=q2.w;
        p[12]=q3.x; p[13]=q3.y; p[14]=q3.z; p[15]=q3.w;

        float v[16];
        #pragma unroll
        for (int ii = 0; ii < 4; ii++) {
            #pragma unroll
            for (int kk = 0; kk < 4; kk++) {
                float vv = fmaf(p[ii*4+0], wr[0*4+kk],
                           fmaf(p[ii*4+1], wr[1*4+kk],
                           fmaf(p[ii*4+2], wr[2*4+kk],
                                p[ii*4+3] * wr[3*4+kk])));
                if (ii == 0 && kk == 3) vv += offw;
                if (ii == 1 && kk == 3) vv += offh;
                v[ii*4+kk] = vv;
            }
        }

        // lg2 = bias2 + sum_d v*(m2iv - v*iv2)   (32 FMA, 4 partials)
        float pa = 0.f, pb = 0.f, pc = 0.f, pd = 0.f;
        #pragma unroll
        for (int ii = 0; ii < 4; ii++) {
            float t0 = fmaf(-v[ii*4+0], iv2[ii*4+0], m2iv[ii*4+0]);
            float t1 = fmaf(-v[ii*4+1], iv2[ii*4+1], m2iv[ii*4+1]);
            float t2 = fmaf(-v[ii*4+2], iv2[ii*4+2], m2iv[ii*4+2]);
            float t3 = fmaf(-v[ii*4+3], iv2[ii*4+3], m2iv[ii*4+3]);
            pa = fmaf(v[ii*4+0], t0, pa);
            pb = fmaf(v[ii*4+1], t1, pb);
            pc = fmaf(v[ii*4+2], t2, pc);
            pd = fmaf(v[ii*4+3], t3, pd);
        }
        const float lg = bias2 + ((pa + pb) + (pc + pd));
        smem[(s & 1) * 352 + c * 11 + o] = lg;
        __syncthreads();

        float lgs[OO];
        #pragma unroll
        for (int j = 0; j < OO; j++) lgs[j] = smem[(s & 1) * 352 + c * 11 + j];
        float m01 = fmaxf(lgs[0], lgs[1]), m23 = fmaxf(lgs[2], lgs[3]);
        float m45 = fmaxf(lgs[4], lgs[5]), m67 = fmaxf(lgs[6], lgs[7]);
        float m89 = fmaxf(lgs[8], lgs[9]);
        const float mx = fmaxf(fmaxf(fmaxf(m01, m23), fmaxf(m45, m67)), m89);
        float ef[OO];
        #pragma unroll
        for (int j = 0; j < OO; j++) ef[j] = EXP2F(lgs[j] - mx);
        const float own = EXP2F(lg - mx);
        float s01 = ef[0]+ef[1], s23 = ef[2]+ef[3], s45 = ef[4]+ef[5];
        float s67 = ef[6]+ef[7], s89 = ef[8]+ef[9];
        const float sum = ((s01+s23) + (s45+s67)) + s89;
        const float rr = own * (a / sum);

        #pragma unroll
        for (int d = 0; d < 16; d++) {
            const float rv = rr * v[d];
            S1[d] += rv;
            S2[d] = fmaf(rv, v[d], S2[d]);
        }
        S0 += rr;
    }

    // ---- epilogue: two-round LDS table (320x17, 21.8KB) + atomics ----
    float* accB = accOut + (size_t)b * OO * 33;
    __syncthreads();                 // logits dead; reuse smem
    #pragma unroll
    for (int k = 0; k < 16; k++) smem[t * 17 + k] = S1[k];
    smem[t * 17 + 16] = S0;
    __syncthreads();
    for (int u = t; u < 170; u += TPB) {
        const int oo = u / 17, kk = u - 17 * oo;
        float s = 0.f;
        #pragma unroll
        for (int cc = 0; cc < 32; cc++) s += smem[(oo * 32 + cc) * 17 + kk];
        atomicAdd(accB + oo * 33 + ((kk < 16) ? kk : 32), s);
    }
    __syncthreads();
    #pragma unroll
    for (int k = 0; k < 16; k++) smem[t * 17 + k] = S2[k];
    __syncthreads();
    for (int u = t; u < 160; u += TPB) {
        const int oo = u >> 4, kk = u & 15;
        float s = 0.f;
        #pragma unroll
        for (int cc = 0; cc < 32; cc++) s += smem[(oo * 32 + cc) * 17 + kk];
        atomicAdd(accB + oo * 33 + 16 + kk, s);
    }
}

__global__ __launch_bounds__(256) void fc_stats(
    const float* __restrict__ acc, const float* __restrict__ beta_a,
    const float* __restrict__ beta_u,
    float* __restrict__ out, float inv_temp)
{
    const int t = threadIdx.x;
    const int b = blockIdx.x;
    if (t >= 160) return;
    const int o = t >> 4, d = t & 15;
    const float* ab = acc + ((size_t)b * OO + o) * 33;
    const float S1 = ab[d], S2 = ab[16 + d], S0 = ab[32];
    const float rs = S0 + EPSF;
    const float mu = S1 / rs;
    float vraw = fmaf(mu * mu, S0, fmaf(-2.f * mu, S1, S2));
    vraw = fmaxf(vraw, 0.f);
    const float var = vraw / rs + EPSF;
    const float lv = __logf(var);
    float sv = lv;
    #pragma unroll
    for (int off = 8; off >= 1; off >>= 1) sv += __shfl_xor(sv, off, 16);
    const float cost = rs * fmaf(0.5f, sv, 16.f * beta_u[o]);
    const float av = 1.f / (1.f + __expf(-inv_temp * (beta_a[o] - cost)));
    out[((size_t)b * OO + o) * 16 + d] = mu;               // pose_out (B,O,16)
    if (d == 0) out[BB * OO * 16 + b * OO + o] = av;       // act_out (B,O)
}

extern "C" void kernel_launch(void* const* d_in, const int* in_sizes, int n_in,
                              void* d_out, int out_size, void* d_ws, size_t ws_size,
                              hipStream_t stream) {
    const float* pose   = (const float*)d_in[0];
    const float* actv   = (const float*)d_in[1];
    const float* wgt    = (const float*)d_in[2];
    const float* beta_a = (const float*)d_in[3];
    const float* beta_u = (const float*)d_in[4];
    float* out = (float*)d_out;
    float* ws  = (float*)d_ws;

    hipMemsetAsync(ws + OFF_ACC, 0, (size_t)3 * ACC_PER_IT * sizeof(float), stream);

    float* acc0 = ws + OFF_ACC;
    float* acc1 = ws + OFF_ACC + ACC_PER_IT;
    float* acc2 = ws + OFF_ACC + 2 * ACC_PER_IT;

    dim3 pblk(TPB);
    fc_pass0<<<dim3(14, BB), pblk, 0, stream>>>(pose, actv, wgt, acc0);
    fc_pass<<<dim3(14, BB), pblk, 0, stream>>>(pose, actv, wgt, acc0, beta_a, beta_u, acc1, 1.0f);
    fc_pass<<<dim3(14, BB), pblk, 0, stream>>>(pose, actv, wgt, acc1, beta_a, beta_u, acc2, 2.0f);
    fc_stats<<<BB, 256, 0, stream>>>(acc2, beta_a, beta_u, out, 3.0f);
}

// Round 13
// 219.107 us; speedup vs baseline: 1.1466x; 1.1466x over previous
//
#include <hip/hip_runtime.h>
#include <hip/hip_bf16.h>

#define BB 64
#define NN 6272      // H*W*C = 196*32
#define OO 10
#define TPB 320      // 32 c x 10 o
#define EPSF 1e-9f
#define LOG2E 1.44269504f
#define HLOG2E 0.72134752f   // 0.5*log2(e)

#define EXP2F(x) __builtin_amdgcn_exp2f(x)   // v_exp_f32

// workspace offsets (floats)
#define ACC_PER_IT 21120            // B*O*33
#define OFF_ACC 0                   // 3 * 21120 = 63360
#define OFF_GMOM 63360              // B*2208 = 141312

// ---------------- pass0a: moments accumulation (R8 body) ----------------
// Ends with atomicAdd into per-b global moment buffer instead of the
// in-block transform (R12 post-mortem: transform duplication per chunk
// block made pass0 the slowest kernel, 72-77us at 19% VALUBusy).
__global__ __launch_bounds__(TPB, 3) void fc_moments(
    const float* __restrict__ pose, const float* __restrict__ actv,
    float* __restrict__ gmom)
{
    __shared__ float smem0[5 * 2208];       // [wave][c][69] slices, 44160 B

    const int t = threadIdx.x;
    const int lane = t & 63;
    const int wv = t >> 6;                  // 0..4
    const int c = lane & 31;
    const int slot = t >> 5;                // 0..9
    const int chunk = blockIdx.x;           // 0..6 (28 hw rows each)
    const int b = blockIdx.y;

    float A1[16], M[40], Vw[4], Vh[4];
    float S0 = 0.f, Uw = 0.f, Uh = 0.f, sw2 = 0.f, sh2 = 0.f;
    #pragma unroll
    for (int k = 0; k < 16; k++) A1[k] = 0.f;
    #pragma unroll
    for (int k = 0; k < 40; k++) M[k] = 0.f;
    #pragma unroll
    for (int k = 0; k < 4; k++) { Vw[k] = 0.f; Vh[k] = 0.f; }

    for (int r = 0; r < 3; r++) {
        const int hl = slot + 10 * r;
        if (hl >= 28) break;                 // slots 8,9 do 2 rows
        const int hw = chunk * 28 + hl;
        const int hi = hw / 14;
        const int wi = hw - hi * 14;
        const float offw = (wi + 0.5f) * (1.0f / 14.0f);
        const float offh = (hi + 0.5f) * (1.0f / 14.0f);
        const size_t row = (size_t)b * NN + (hw << 5) + c;

        const float4* pp = (const float4*)(pose + row * 16);
        float4 q0 = pp[0], q1 = pp[1], q2 = pp[2], q3 = pp[3];
        const float a = actv[row];
        const float ra = 0.1f * a;
        const float raw = ra * offw, rah = ra * offh;
        S0 += ra; Uw += raw; Uh += rah;
        sw2 = fmaf(raw, offw, sw2); sh2 = fmaf(rah, offh, sh2);

        #define FOLD_I(qq, i)                                              \
        {                                                                  \
            const float x = qq.x, y = qq.y, z = qq.z, w = qq.w;            \
            const float t0 = ra * x, t1 = ra * y, t2 = ra * z, t3 = ra * w;\
            A1[i*4+0] += t0; A1[i*4+1] += t1;                              \
            A1[i*4+2] += t2; A1[i*4+3] += t3;                              \
            M[i*10+0] = fmaf(t0, x, M[i*10+0]);                            \
            M[i*10+1] = fmaf(t0, y, M[i*10+1]);                            \
            M[i*10+2] = fmaf(t0, z, M[i*10+2]);                            \
            M[i*10+3] = fmaf(t0, w, M[i*10+3]);                            \
            M[i*10+4] = fmaf(t1, y, M[i*10+4]);                            \
            M[i*10+5] = fmaf(t1, z, M[i*10+5]);                            \
            M[i*10+6] = fmaf(t1, w, M[i*10+6]);                            \
            M[i*10+7] = fmaf(t2, z, M[i*10+7]);                            \
            M[i*10+8] = fmaf(t2, w, M[i*10+8]);                            \
            M[i*10+9] = fmaf(t3, w, M[i*10+9]);                            \
        }
        FOLD_I(q0, 0) FOLD_I(q1, 1) FOLD_I(q2, 2) FOLD_I(q3, 3)
        #undef FOLD_I
        Vw[0] = fmaf(raw, q0.x, Vw[0]); Vw[1] = fmaf(raw, q0.y, Vw[1]);
        Vw[2] = fmaf(raw, q0.z, Vw[2]); Vw[3] = fmaf(raw, q0.w, Vw[3]);
        Vh[0] = fmaf(rah, q1.x, Vh[0]); Vh[1] = fmaf(rah, q1.y, Vh[1]);
        Vh[2] = fmaf(rah, q1.z, Vh[2]); Vh[3] = fmaf(rah, q1.w, Vh[3]);
    }

    float* myrow = &smem0[wv * 2208 + c * 69];
    #define FOLDW(arr, n, base)                                            \
    _Pragma("unroll")                                                      \
    for (int k2 = 0; k2 < n; k2++) {                                       \
        float x = arr[k2] + __shfl_xor(arr[k2], 32, 64);                   \
        if (lane < 32) myrow[base + k2] = x;                               \
    }
    FOLDW(A1, 16, 0) FOLDW(M, 40, 16) FOLDW(Vw, 4, 56) FOLDW(Vh, 4, 60)
    #undef FOLDW
    {
        float x0 = S0 + __shfl_xor(S0, 32, 64);
        float x1 = Uw + __shfl_xor(Uw, 32, 64);
        float x2 = Uh + __shfl_xor(Uh, 32, 64);
        float x3 = sw2 + __shfl_xor(sw2, 32, 64);
        float x4 = sh2 + __shfl_xor(sh2, 32, 64);
        if (lane < 32) {
            myrow[64] = x0; myrow[65] = x1; myrow[66] = x2;
            myrow[67] = x3; myrow[68] = x4;
        }
    }
    __syncthreads();
    float* gb = gmom + (size_t)b * 2208;
    for (int e = t; e < 2208; e += TPB) {
        const float s = smem0[e] + smem0[2208 + e] + smem0[2*2208 + e]
                      + smem0[3*2208 + e] + smem0[4*2208 + e];
        atomicAdd(&gb[e], s);
    }
}

// ---------------- pass0b: transform, ONCE per b (grid 64) ----------------
__global__ __launch_bounds__(TPB) void fc_transform(
    const float* __restrict__ gmom, const float* __restrict__ wgt,
    float* __restrict__ acc)
{
    __shared__ float smem0[2208];
    const int t = threadIdx.x;
    const int b = blockIdx.x;

    const float* gb = gmom + (size_t)b * 2208;
    for (int e = t; e < 2208; e += TPB) smem0[e] = gb[e];
    __syncthreads();

    const int oo = t >> 5, k = t & 31;
    float* ab = acc + ((size_t)b * OO + oo) * 33;
    if (k < 16) {
        const int i = k >> 2, kk = k & 3;
        float s = 0.f, s0acc = 0.f;
        #pragma unroll 4
        for (int cc = 0; cc < 32; cc++) {
            const float* mc = &smem0[cc * 69];
            const float* wc = wgt + cc * 160 + oo * 16 + kk;
            const float w0 = wc[0], w1 = wc[4], w2 = wc[8], w3 = wc[12];
            s += w0*mc[i*4+0] + w1*mc[i*4+1] + w2*mc[i*4+2] + w3*mc[i*4+3];
            if (k == 3) s += mc[65];
            if (k == 7) s += mc[66];
            if (k == 0) s0acc += mc[64];
        }
        ab[k] = s;
        if (k == 0) ab[32] = s0acc;
    } else {
        const int km = k - 16, i = km >> 2, kk = km & 3;
        float s = 0.f;
        #pragma unroll 4
        for (int cc = 0; cc < 32; cc++) {
            const float* mc = &smem0[cc * 69];
            const float* mi = mc + 16 + i * 10;
            const float* wc = wgt + cc * 160 + oo * 16 + kk;
            const float w0 = wc[0], w1 = wc[4], w2 = wc[8], w3 = wc[12];
            float q = w0*(w0*mi[0] + 2.f*(w1*mi[1] + w2*mi[2] + w3*mi[3]))
                    + w1*(w1*mi[4] + 2.f*(w2*mi[5] + w3*mi[6]))
                    + w2*(w2*mi[7] + 2.f*w3*mi[8])
                    + w3*(w3*mi[9]);
            s += q;
            if (km == 3) s += 2.f*(w0*mc[56]+w1*mc[57]+w2*mc[58]+w3*mc[59]) + mc[67];
            if (km == 7) s += 2.f*(w0*mc[60]+w1*mc[61]+w2*mc[62]+w3*mc[63]) + mc[68];
        }
        ab[k] = s;
    }
}

// ---------------- iters 1-2: 14-step log2-domain body (R12, proven) ----------------
__global__ __launch_bounds__(TPB, 3) void fc_pass(
    const float* __restrict__ pose, const float* __restrict__ actv,
    const float* __restrict__ wgt,
    const float* __restrict__ accPrev,
    const float* __restrict__ beta_a, const float* __restrict__ beta_u,
    float* __restrict__ accOut, float inv_temp)
{
    __shared__ float smem[TPB * 17];   // logits: first 704 floats; epilogue table 5440

    const int t = threadIdx.x;
    const int c = t & 31;
    const int o = t >> 5;               // 0..9
    const int hi = blockIdx.x;          // 0..13
    const int b  = blockIdx.y;

    float wr[16];
    {
        const float4* wp = (const float4*)(wgt + ((c * OO + o) << 4));
        float4 a0 = wp[0], a1 = wp[1], a2 = wp[2], a3 = wp[3];
        wr[0]=a0.x; wr[1]=a0.y; wr[2]=a0.z; wr[3]=a0.w;
        wr[4]=a1.x; wr[5]=a1.y; wr[6]=a1.z; wr[7]=a1.w;
        wr[8]=a2.x; wr[9]=a2.y; wr[10]=a2.z; wr[11]=a2.w;
        wr[12]=a3.x; wr[13]=a3.y; wr[14]=a3.z; wr[15]=a3.w;
    }

    // fused stats from previous pass's acc, pre-transformed to log2 domain
    float iv2[16], m2iv[16], bias2;
    {
        const float* ab = accPrev + ((size_t)b * OO + o) * 33;
        const float S0p = ab[32];
        const float rs = S0p + EPSF;
        const float rsi = 1.f / rs;
        float sv = 0.f, csum = 0.f;
        #pragma unroll
        for (int d = 0; d < 16; d++) {
            const float s1 = ab[d], s2 = ab[16 + d];
            const float m = s1 * rsi;
            float vraw = fmaf(m * m, S0p, fmaf(-2.f * m, s1, s2));
            vraw = fmaxf(vraw, 0.f);
            const float var = fmaf(vraw, rsi, EPSF);
            sv += __logf(var);
            const float ivd = 1.f / var;
            const float i2 = ivd * HLOG2E;
            iv2[d] = i2;
            m2iv[d] = 2.f * m * i2;
            csum = fmaf(m * m, i2, csum);
        }
        const float cost = rs * fmaf(0.5f, sv, 16.f * beta_u[o]);
        const float act = 1.f / (1.f + __expf(-inv_temp * (beta_a[o] - cost)));
        const float biasN = __logf(act + EPSF) - 0.5f * sv;
        bias2 = fmaf(biasN, LOG2E, -csum);
    }

    float S1[16], S2[16], S0 = 0.f;
    #pragma unroll
    for (int d = 0; d < 16; d++) { S1[d] = 0.f; S2[d] = 0.f; }

    const size_t baseN = (size_t)b * NN + hi * 448;
    const float offh = (hi + 0.5f) * (1.0f / 14.0f);

    for (int s = 0; s < 14; s++) {
        const float offw = (s + 0.5f) * (1.0f / 14.0f);
        const int n = s * 32 + c;

        const float4* pp = (const float4*)(pose + (baseN + n) * 16);
        float4 q0 = pp[0], q1 = pp[1], q2 = pp[2], q3 = pp[3];
        const float a = actv[baseN + n];

        float p[16];
        p[0]=q0.x; p[1]=q0.y; p[2]=q0.z; p[3]=q0.w;
        p[4]=q1.x; p[5]=q1.y; p[6]=q1.z; p[7]=q1.w;
        p[8]=q2.x; p[9]=q2.y; p[10]=q2.z; p[11]=q2.w;
        p[12]=q3.x; p[13]=q3.y; p[14]=q3.z; p[15]=q3.w;

        float v[16];
        #pragma unroll
        for (int ii = 0; ii < 4; ii++) {
            #pragma unroll
            for (int kk = 0; kk < 4; kk++) {
                float vv = fmaf(p[ii*4+0], wr[0*4+kk],
                           fmaf(p[ii*4+1], wr[1*4+kk],
                           fmaf(p[ii*4+2], wr[2*4+kk],
                                p[ii*4+3] * wr[3*4+kk])));
                if (ii == 0 && kk == 3) vv += offw;
                if (ii == 1 && kk == 3) vv += offh;
                v[ii*4+kk] = vv;
            }
        }

        // lg2 = bias2 + sum_d v*(m2iv - v*iv2)   (32 FMA, 4 partials)
        float pa = 0.f, pb = 0.f, pc = 0.f, pd = 0.f;
        #pragma unroll
        for (int ii = 0; ii < 4; ii++) {
            float t0 = fmaf(-v[ii*4+0], iv2[ii*4+0], m2iv[ii*4+0]);
            float t1 = fmaf(-v[ii*4+1], iv2[ii*4+1], m2iv[ii*4+1]);
            float t2 = fmaf(-v[ii*4+2], iv2[ii*4+2], m2iv[ii*4+2]);
            float t3 = fmaf(-v[ii*4+3], iv2[ii*4+3], m2iv[ii*4+3]);
            pa = fmaf(v[ii*4+0], t0, pa);
            pb = fmaf(v[ii*4+1], t1, pb);
            pc = fmaf(v[ii*4+2], t2, pc);
            pd = fmaf(v[ii*4+3], t3, pd);
        }
        const float lg = bias2 + ((pa + pb) + (pc + pd));
        smem[(s & 1) * 352 + c * 11 + o] = lg;
        __syncthreads();

        float lgs[OO];
        #pragma unroll
        for (int j = 0; j < OO; j++) lgs[j] = smem[(s & 1) * 352 + c * 11 + j];
        float m01 = fmaxf(lgs[0], lgs[1]), m23 = fmaxf(lgs[2], lgs[3]);
        float m45 = fmaxf(lgs[4], lgs[5]), m67 = fmaxf(lgs[6], lgs[7]);
        float m89 = fmaxf(lgs[8], lgs[9]);
        const float mx = fmaxf(fmaxf(fmaxf(m01, m23), fmaxf(m45, m67)), m89);
        float ef[OO];
        #pragma unroll
        for (int j = 0; j < OO; j++) ef[j] = EXP2F(lgs[j] - mx);
        const float own = EXP2F(lg - mx);
        float s01 = ef[0]+ef[1], s23 = ef[2]+ef[3], s45 = ef[4]+ef[5];
        float s67 = ef[6]+ef[7], s89 = ef[8]+ef[9];
        const float sum = ((s01+s23) + (s45+s67)) + s89;
        const float rr = own * (a / sum);

        #pragma unroll
        for (int d = 0; d < 16; d++) {
            const float rv = rr * v[d];
            S1[d] += rv;
            S2[d] = fmaf(rv, v[d], S2[d]);
        }
        S0 += rr;
    }

    // ---- epilogue: two-round LDS table (320x17, 21.8KB) + atomics ----
    float* accB = accOut + (size_t)b * OO * 33;
    __syncthreads();                 // logits dead; reuse smem
    #pragma unroll
    for (int k = 0; k < 16; k++) smem[t * 17 + k] = S1[k];
    smem[t * 17 + 16] = S0;
    __syncthreads();
    for (int u = t; u < 170; u += TPB) {
        const int oo = u / 17, kk = u - 17 * oo;
        float s = 0.f;
        #pragma unroll
        for (int cc = 0; cc < 32; cc++) s += smem[(oo * 32 + cc) * 17 + kk];
        atomicAdd(accB + oo * 33 + ((kk < 16) ? kk : 32), s);
    }
    __syncthreads();
    #pragma unroll
    for (int k = 0; k < 16; k++) smem[t * 17 + k] = S2[k];
    __syncthreads();
    for (int u = t; u < 160; u += TPB) {
        const int oo = u >> 4, kk = u & 15;
        float s = 0.f;
        #pragma unroll
        for (int cc = 0; cc < 32; cc++) s += smem[(oo * 32 + cc) * 17 + kk];
        atomicAdd(accB + oo * 33 + 16 + kk, s);
    }
}

__global__ __launch_bounds__(256) void fc_stats(
    const float* __restrict__ acc, const float* __restrict__ beta_a,
    const float* __restrict__ beta_u,
    float* __restrict__ out, float inv_temp)
{
    const int t = threadIdx.x;
    const int b = blockIdx.x;
    if (t >= 160) return;
    const int o = t >> 4, d = t & 15;
    const float* ab = acc + ((size_t)b * OO + o) * 33;
    const float S1 = ab[d], S2 = ab[16 + d], S0 = ab[32];
    const float rs = S0 + EPSF;
    const float mu = S1 / rs;
    float vraw = fmaf(mu * mu, S0, fmaf(-2.f * mu, S1, S2));
    vraw = fmaxf(vraw, 0.f);
    const float var = vraw / rs + EPSF;
    const float lv = __logf(var);
    float sv = lv;
    #pragma unroll
    for (int off = 8; off >= 1; off >>= 1) sv += __shfl_xor(sv, off, 16);
    const float cost = rs * fmaf(0.5f, sv, 16.f * beta_u[o]);
    const float av = 1.f / (1.f + __expf(-inv_temp * (beta_a[o] - cost)));
    out[((size_t)b * OO + o) * 16 + d] = mu;               // pose_out (B,O,16)
    if (d == 0) out[BB * OO * 16 + b * OO + o] = av;       // act_out (B,O)
}

extern "C" void kernel_launch(void* const* d_in, const int* in_sizes, int n_in,
                              void* d_out, int out_size, void* d_ws, size_t ws_size,
                              hipStream_t stream) {
    const float* pose   = (const float*)d_in[0];
    const float* actv   = (const float*)d_in[1];
    const float* wgt    = (const float*)d_in[2];
    const float* beta_a = (const float*)d_in[3];
    const float* beta_u = (const float*)d_in[4];
    float* out = (float*)d_out;
    float* ws  = (float*)d_ws;

    float* acc0 = ws + OFF_ACC;
    float* acc1 = ws + OFF_ACC + ACC_PER_IT;
    float* acc2 = ws + OFF_ACC + 2 * ACC_PER_IT;
    float* gmom = ws + OFF_GMOM;

    // zero acc1, acc2 (epilogue atomics) and gmom (moment atomics);
    // acc0 is fully written by fc_transform.
    hipMemsetAsync(acc1, 0, (size_t)(2 * ACC_PER_IT + BB * 2208) * sizeof(float), stream);

    dim3 pblk(TPB);
    fc_moments<<<dim3(7, BB), pblk, 0, stream>>>(pose, actv, gmom);
    fc_transform<<<BB, pblk, 0, stream>>>(gmom, wgt, acc0);
    fc_pass<<<dim3(14, BB), pblk, 0, stream>>>(pose, actv, wgt, acc0, beta_a, beta_u, acc1, 1.0f);
    fc_pass<<<dim3(14, BB), pblk, 0, stream>>>(pose, actv, wgt, acc1, beta_a, beta_u, acc2, 2.0f);
    fc_stats<<<BB, 256, 0, stream>>>(acc2, beta_a, beta_u, out, 3.0f);
}